// Round 1
// baseline (2676.917 us; speedup 1.0000x reference)
//
#include <hip/hip_runtime.h>
#include <math.h>

#define G_N 50000
#define D_S 3
#define HC 64
#define IN_DIM 256
#define OUT_DIM 40
#define NL 4
#define NNZV 2400000
#define NN (G_N * D_S)   // 150000

__device__ __forceinline__ float elu_f(float v) {
    return v > 0.0f ? v : expm1f(v);
}

// ---------------- lin1: out[g, j] = elu(sum_k x[g,k] * W[j,k] + b[j]),  [50000,256]x[192,256]^T
__global__ __launch_bounds__(256) void lin1_gemm(const float* __restrict__ x,
        const float* __restrict__ W, const float* __restrict__ b,
        float* __restrict__ out) {
    const int K = IN_DIM;          // 256
    __shared__ float As[32][65];   // [k][row]
    __shared__ float Bs[32][65];   // [k][col]
    int tid = threadIdx.x;
    int tx = tid & 15, ty = tid >> 4;
    int m0 = blockIdx.x * 64;
    int n0 = blockIdx.y * 64;

    float acc[4][4] = {};

    int kslot = tid & 7;     // 8 slots * 4 floats = 32 k
    int row   = tid >> 3;    // 32 rows per pass

    for (int k0 = 0; k0 < K; k0 += 32) {
        #pragma unroll
        for (int pass = 0; pass < 2; ++pass) {
            int r = row + pass * 32;
            int gr = m0 + r;
            float4 v = make_float4(0.f, 0.f, 0.f, 0.f);
            if (gr < G_N) v = *(const float4*)(x + (size_t)gr * K + k0 + kslot * 4);
            As[kslot*4+0][r] = v.x; As[kslot*4+1][r] = v.y;
            As[kslot*4+2][r] = v.z; As[kslot*4+3][r] = v.w;

            int j = r;  // 192 is a multiple of 64; no col guard needed
            float4 w4 = *(const float4*)(W + (size_t)(n0 + j) * K + k0 + kslot * 4);
            Bs[kslot*4+0][j] = w4.x; Bs[kslot*4+1][j] = w4.y;
            Bs[kslot*4+2][j] = w4.z; Bs[kslot*4+3][j] = w4.w;
        }
        __syncthreads();
        #pragma unroll 8
        for (int k = 0; k < 32; ++k) {
            float4 a4 = *(const float4*)&As[k][ty*4];
            float4 b4 = *(const float4*)&Bs[k][tx*4];
            float av[4] = {a4.x, a4.y, a4.z, a4.w};
            float bv[4] = {b4.x, b4.y, b4.z, b4.w};
            #pragma unroll
            for (int i = 0; i < 4; ++i)
                #pragma unroll
                for (int j = 0; j < 4; ++j)
                    acc[i][j] = fmaf(av[i], bv[j], acc[i][j]);
        }
        __syncthreads();
    }

    float4 bias = *(const float4*)(b + n0 + tx*4);
    float bi[4] = {bias.x, bias.y, bias.z, bias.w};
    #pragma unroll
    for (int i = 0; i < 4; ++i) {
        int gr = m0 + ty*4 + i;
        if (gr < G_N) {
            float4 o;
            o.x = elu_f(acc[i][0] + bi[0]);
            o.y = elu_f(acc[i][1] + bi[1]);
            o.z = elu_f(acc[i][2] + bi[2]);
            o.w = elu_f(acc[i][3] + bi[3]);
            *(float4*)(out + (size_t)gr * 192 + n0 + tx*4) = o;
        }
    }
}

// ---------------- transform: out[n,j] = sum_c A[n,c]*Wr[j,c];  A[g*3+e, c] = sum_d lw[e,d]*h0[(g*3+d), c]
__global__ __launch_bounds__(256) void transform_gemm(const float* __restrict__ h0,
        const float* __restrict__ lw, const float* __restrict__ Wr,
        float* __restrict__ out) {
    __shared__ float As[64][65];   // [k][row]
    __shared__ float Bs[64][65];   // [k][col j]
    int tid = threadIdx.x;
    int tx = tid & 15, ty = tid >> 4;
    int r0 = blockIdx.x * 64;

    float L[9];
    #pragma unroll
    for (int i = 0; i < 9; ++i) L[i] = lw[i];

    int kslot = tid & 15;    // 16 * 4 = 64 k
    int rr    = tid >> 4;    // 16 rows per pass

    #pragma unroll
    for (int pass = 0; pass < 4; ++pass) {
        int r = rr + pass * 16;
        int gr = r0 + r;
        float4 v = make_float4(0.f, 0.f, 0.f, 0.f);
        if (gr < NN) {
            int g = gr / 3;
            int e = gr - g * 3;
            const float* base = h0 + (size_t)(g * 3) * HC + kslot * 4;
            float4 a0 = *(const float4*)(base);
            float4 a1 = *(const float4*)(base + HC);
            float4 a2 = *(const float4*)(base + 2 * HC);
            float l0 = L[e*3+0], l1 = L[e*3+1], l2 = L[e*3+2];
            v.x = l0*a0.x + l1*a1.x + l2*a2.x;
            v.y = l0*a0.y + l1*a1.y + l2*a2.y;
            v.z = l0*a0.z + l1*a1.z + l2*a2.z;
            v.w = l0*a0.w + l1*a1.w + l2*a2.w;
        }
        As[kslot*4+0][r] = v.x; As[kslot*4+1][r] = v.y;
        As[kslot*4+2][r] = v.z; As[kslot*4+3][r] = v.w;

        int j = r;
        float4 w4 = *(const float4*)(Wr + (size_t)j * HC + kslot * 4);
        Bs[kslot*4+0][j] = w4.x; Bs[kslot*4+1][j] = w4.y;
        Bs[kslot*4+2][j] = w4.z; Bs[kslot*4+3][j] = w4.w;
    }
    __syncthreads();

    float acc[4][4] = {};
    #pragma unroll 8
    for (int k = 0; k < 64; ++k) {
        float4 a4 = *(const float4*)&As[k][ty*4];
        float4 b4 = *(const float4*)&Bs[k][tx*4];
        float av[4] = {a4.x, a4.y, a4.z, a4.w};
        float bv[4] = {b4.x, b4.y, b4.z, b4.w};
        #pragma unroll
        for (int i = 0; i < 4; ++i)
            #pragma unroll
            for (int j = 0; j < 4; ++j)
                acc[i][j] = fmaf(av[i], bv[j], acc[i][j]);
    }

    #pragma unroll
    for (int i = 0; i < 4; ++i) {
        int gr = r0 + ty*4 + i;
        if (gr < NN) {
            float4 o = make_float4(acc[i][0], acc[i][1], acc[i][2], acc[i][3]);
            *(float4*)(out + (size_t)gr * HC + tx*4) = o;
        }
    }
}

// ---------------- SpMM scatter: outc[r, lane] += v * t[c, lane]
__global__ __launch_bounds__(256) void spmm_atomic(const int* __restrict__ rows,
        const int* __restrict__ cols, const float* __restrict__ vals,
        const float* __restrict__ t, float* __restrict__ outc, int nwaves) {
    int w = blockIdx.x * 4 + (threadIdx.x >> 6);
    int lane = threadIdx.x & 63;
    for (int i = w; i < NNZV; i += nwaves) {
        int r = rows[i];
        int c = cols[i];
        float v = vals[i];
        float hv = t[(size_t)c * HC + lane];
        atomicAdd(outc + (size_t)r * HC + lane, v * hv);
    }
}

// ---------------- epilogue: h0 = gate*h0 - elu(c)
__global__ __launch_bounds__(256) void epilogue_k(float* __restrict__ h0buf,
        const float* __restrict__ cbuf, const float* __restrict__ eps, int l) {
    int stride = gridDim.x * blockDim.x;
    for (int idx = blockIdx.x * blockDim.x + threadIdx.x; idx < NN * HC; idx += stride) {
        float cv = cbuf[idx];
        float hnew = cv > 0.0f ? cv : expm1f(cv);
        int d = (idx >> 6) % 3;
        float gate = 1.0f + tanhf(eps[l * 3 + d]);
        h0buf[idx] = gate * h0buf[idx] - hnew;
    }
}

// ---------------- lin2 + log_softmax: one wave per graph node
__global__ __launch_bounds__(256) void lin2_logsoftmax(const float* __restrict__ h,
        const float* __restrict__ W, const float* __restrict__ b,
        float* __restrict__ out) {
    int wid = blockIdx.x * 4 + (threadIdx.x >> 6);
    int lane = threadIdx.x & 63;
    if (wid >= G_N) return;
    float acc = 0.0f;
    const float* hr = h + (size_t)wid * 192;
    if (lane < OUT_DIM) {
        const float* wr_ = W + (size_t)lane * 192;
        #pragma unroll 4
        for (int k = 0; k < 192; k += 4) {
            float4 hv = *(const float4*)(hr + k);
            float4 wv = *(const float4*)(wr_ + k);
            acc = fmaf(hv.x, wv.x, acc);
            acc = fmaf(hv.y, wv.y, acc);
            acc = fmaf(hv.z, wv.z, acc);
            acc = fmaf(hv.w, wv.w, acc);
        }
        acc += b[lane];
    }
    float m = (lane < OUT_DIM) ? acc : -INFINITY;
    #pragma unroll
    for (int off = 32; off; off >>= 1) m = fmaxf(m, __shfl_xor(m, off));
    float e = (lane < OUT_DIM) ? expf(acc - m) : 0.0f;
    float s = e;
    #pragma unroll
    for (int off = 32; off; off >>= 1) s += __shfl_xor(s, off);
    if (lane < OUT_DIM) out[(size_t)wid * OUT_DIM + lane] = acc - m - logf(s);
}

extern "C" void kernel_launch(void* const* d_in, const int* in_sizes, int n_in,
                              void* d_out, int out_size, void* d_ws, size_t ws_size,
                              hipStream_t stream) {
    const float* x      = (const float*)d_in[0];
    const int*   rows   = (const int*)d_in[1];
    const int*   cols   = (const int*)d_in[2];
    const float* vals   = (const float*)d_in[3];
    const float* lin1_w = (const float*)d_in[4];
    const float* lin1_b = (const float*)d_in[5];
    const float* left_w = (const float*)d_in[6];
    const float* right_w= (const float*)d_in[7];
    const float* eps    = (const float*)d_in[8];
    const float* lin2_w = (const float*)d_in[9];
    const float* lin2_b = (const float*)d_in[10];
    float* out = (float*)d_out;

    size_t bufElems = (size_t)NN * HC;   // 9.6M floats
    float* h0 = (float*)d_ws;
    float* t  = h0 + bufElems;
    float* c  = t + bufElems;

    dim3 b256(256);

    // lin1 -> h0  ([G,192] flat == [N,64] flat)
    lin1_gemm<<<dim3((G_N + 63) / 64, 3), b256, 0, stream>>>(x, lin1_w, lin1_b, h0);

    for (int l = 0; l < NL; ++l) {
        transform_gemm<<<dim3((NN + 63) / 64), b256, 0, stream>>>(
            h0, left_w + l * 9, right_w + l * HC * HC, t);
        hipMemsetAsync(c, 0, bufElems * sizeof(float), stream);
        int nblocks = 2048;
        spmm_atomic<<<dim3(nblocks), b256, 0, stream>>>(rows, cols, vals, t, c, nblocks * 4);
        epilogue_k<<<dim3(1024), b256, 0, stream>>>(h0, c, eps, l);
    }

    lin2_logsoftmax<<<dim3((G_N + 3) / 4), b256, 0, stream>>>(h0, lin2_w, lin2_b, out);
}

// Round 2
// 1713.888 us; speedup vs baseline: 1.5619x; 1.5619x over previous
//
#include <hip/hip_runtime.h>
#include <math.h>

#define G_N 50000
#define D_S 3
#define HC 64
#define IN_DIM 256
#define OUT_DIM 40
#define NL 4
#define NNZV 2400000
#define NN (G_N * D_S)   // 150000

__device__ __forceinline__ float elu_f(float v) {
    return v > 0.0f ? v : expm1f(v);
}

// ---------------- lin1: out[g, j] = elu(sum_k x[g,k] * W[j,k] + b[j])
__global__ __launch_bounds__(256) void lin1_gemm(const float* __restrict__ x,
        const float* __restrict__ W, const float* __restrict__ b,
        float* __restrict__ out) {
    const int K = IN_DIM;
    __shared__ float As[32][65];
    __shared__ float Bs[32][65];
    int tid = threadIdx.x;
    int tx = tid & 15, ty = tid >> 4;
    int m0 = blockIdx.x * 64;
    int n0 = blockIdx.y * 64;

    float acc[4][4] = {};
    int kslot = tid & 7;
    int row   = tid >> 3;

    for (int k0 = 0; k0 < K; k0 += 32) {
        #pragma unroll
        for (int pass = 0; pass < 2; ++pass) {
            int r = row + pass * 32;
            int gr = m0 + r;
            float4 v = make_float4(0.f, 0.f, 0.f, 0.f);
            if (gr < G_N) v = *(const float4*)(x + (size_t)gr * K + k0 + kslot * 4);
            As[kslot*4+0][r] = v.x; As[kslot*4+1][r] = v.y;
            As[kslot*4+2][r] = v.z; As[kslot*4+3][r] = v.w;

            int j = r;
            float4 w4 = *(const float4*)(W + (size_t)(n0 + j) * K + k0 + kslot * 4);
            Bs[kslot*4+0][j] = w4.x; Bs[kslot*4+1][j] = w4.y;
            Bs[kslot*4+2][j] = w4.z; Bs[kslot*4+3][j] = w4.w;
        }
        __syncthreads();
        #pragma unroll 8
        for (int k = 0; k < 32; ++k) {
            float4 a4 = *(const float4*)&As[k][ty*4];
            float4 b4 = *(const float4*)&Bs[k][tx*4];
            float av[4] = {a4.x, a4.y, a4.z, a4.w};
            float bv[4] = {b4.x, b4.y, b4.z, b4.w};
            #pragma unroll
            for (int i = 0; i < 4; ++i)
                #pragma unroll
                for (int j = 0; j < 4; ++j)
                    acc[i][j] = fmaf(av[i], bv[j], acc[i][j]);
        }
        __syncthreads();
    }

    float4 bias = *(const float4*)(b + n0 + tx*4);
    float bi[4] = {bias.x, bias.y, bias.z, bias.w};
    #pragma unroll
    for (int i = 0; i < 4; ++i) {
        int gr = m0 + ty*4 + i;
        if (gr < G_N) {
            float4 o;
            o.x = elu_f(acc[i][0] + bi[0]);
            o.y = elu_f(acc[i][1] + bi[1]);
            o.z = elu_f(acc[i][2] + bi[2]);
            o.w = elu_f(acc[i][3] + bi[3]);
            *(float4*)(out + (size_t)gr * 192 + n0 + tx*4) = o;
        }
    }
}

// ---------------- transform: out[n,j] = sum_c A[n,c]*Wr[j,c];  A[g*3+e,c] = sum_d lw[e,d]*h0[g*3+d,c]
__global__ __launch_bounds__(256) void transform_gemm(const float* __restrict__ h0,
        const float* __restrict__ lw, const float* __restrict__ Wr,
        float* __restrict__ out) {
    __shared__ float As[64][65];
    __shared__ float Bs[64][65];
    int tid = threadIdx.x;
    int tx = tid & 15, ty = tid >> 4;
    int r0 = blockIdx.x * 64;

    float L[9];
    #pragma unroll
    for (int i = 0; i < 9; ++i) L[i] = lw[i];

    int kslot = tid & 15;
    int rr    = tid >> 4;

    #pragma unroll
    for (int pass = 0; pass < 4; ++pass) {
        int r = rr + pass * 16;
        int gr = r0 + r;
        float4 v = make_float4(0.f, 0.f, 0.f, 0.f);
        if (gr < NN) {
            int g = gr / 3;
            int e = gr - g * 3;
            const float* base = h0 + (size_t)(g * 3) * HC + kslot * 4;
            float4 a0 = *(const float4*)(base);
            float4 a1 = *(const float4*)(base + HC);
            float4 a2 = *(const float4*)(base + 2 * HC);
            float l0 = L[e*3+0], l1 = L[e*3+1], l2 = L[e*3+2];
            v.x = l0*a0.x + l1*a1.x + l2*a2.x;
            v.y = l0*a0.y + l1*a1.y + l2*a2.y;
            v.z = l0*a0.z + l1*a1.z + l2*a2.z;
            v.w = l0*a0.w + l1*a1.w + l2*a2.w;
        }
        As[kslot*4+0][r] = v.x; As[kslot*4+1][r] = v.y;
        As[kslot*4+2][r] = v.z; As[kslot*4+3][r] = v.w;

        int j = r;
        float4 w4 = *(const float4*)(Wr + (size_t)j * HC + kslot * 4);
        Bs[kslot*4+0][j] = w4.x; Bs[kslot*4+1][j] = w4.y;
        Bs[kslot*4+2][j] = w4.z; Bs[kslot*4+3][j] = w4.w;
    }
    __syncthreads();

    float acc[4][4] = {};
    #pragma unroll 8
    for (int k = 0; k < 64; ++k) {
        float4 a4 = *(const float4*)&As[k][ty*4];
        float4 b4 = *(const float4*)&Bs[k][tx*4];
        float av[4] = {a4.x, a4.y, a4.z, a4.w};
        float bv[4] = {b4.x, b4.y, b4.z, b4.w};
        #pragma unroll
        for (int i = 0; i < 4; ++i)
            #pragma unroll
            for (int j = 0; j < 4; ++j)
                acc[i][j] = fmaf(av[i], bv[j], acc[i][j]);
    }

    #pragma unroll
    for (int i = 0; i < 4; ++i) {
        int gr = r0 + ty*4 + i;
        if (gr < NN) {
            float4 o = make_float4(acc[i][0], acc[i][1], acc[i][2], acc[i][3]);
            *(float4*)(out + (size_t)gr * HC + tx*4) = o;
        }
    }
}

// ---------------- CSR build ----------------
__global__ __launch_bounds__(256) void hist_k(const int* __restrict__ rows, int* __restrict__ cnt) {
    int i = blockIdx.x * 256 + threadIdx.x;
    if (i < NNZV) atomicAdd(&cnt[rows[i]], 1);
}

// block = 256 threads, 1024 elements; local exclusive scan + block sum
__global__ __launch_bounds__(256) void scan_block_k(const int* __restrict__ cnt,
        int* __restrict__ rp, int* __restrict__ bsum) {
    __shared__ int s[256];
    int base = blockIdx.x * 1024;
    int t = threadIdx.x;
    int v[4]; int sum = 0;
    #pragma unroll
    for (int j = 0; j < 4; ++j) {
        int idx = base + t * 4 + j;
        v[j] = (idx < NN) ? cnt[idx] : 0;
        sum += v[j];
    }
    s[t] = sum; __syncthreads();
    #pragma unroll
    for (int off = 1; off < 256; off <<= 1) {
        int x = 0;
        if (t >= off) x = s[t - off];
        __syncthreads();
        if (t >= off) s[t] += x;
        __syncthreads();
    }
    int excl = s[t] - sum;
    if (t == 255) bsum[blockIdx.x] = s[255];
    int run = excl;
    #pragma unroll
    for (int j = 0; j < 4; ++j) {
        int idx = base + t * 4 + j;
        if (idx < NN) rp[idx] = run;
        run += v[j];
    }
}

__global__ __launch_bounds__(256) void scan_top_k(int* __restrict__ bsum, int nb) {
    __shared__ int s[256];
    int t = threadIdx.x;
    int v = (t < nb) ? bsum[t] : 0;
    s[t] = v; __syncthreads();
    #pragma unroll
    for (int off = 1; off < 256; off <<= 1) {
        int x = 0;
        if (t >= off) x = s[t - off];
        __syncthreads();
        if (t >= off) s[t] += x;
        __syncthreads();
    }
    if (t < nb) bsum[t] = s[t] - v;
}

__global__ __launch_bounds__(256) void scan_add_k(int* __restrict__ rp, const int* __restrict__ bsum) {
    int idx = blockIdx.x * 256 + threadIdx.x;
    if (idx < NN) rp[idx] += bsum[idx >> 10];
    else if (idx == NN) rp[NN] = NNZV;
}

__global__ __launch_bounds__(256) void scatter_k(const int* __restrict__ rows,
        const int* __restrict__ cols, const float* __restrict__ vals,
        int* __restrict__ wo, int2* __restrict__ pcv) {
    int i = blockIdx.x * 256 + threadIdx.x;
    if (i < NNZV) {
        int r = rows[i];
        int p = atomicAdd(&wo[r], 1);
        pcv[p] = make_int2(cols[i], __float_as_int(vals[i]));
    }
}

// ---------------- fused CSR SpMM + elu + gated residual: h0 = gate*h0 - elu(L@t)
__global__ __launch_bounds__(256) void spmm_csr_fused(const int* __restrict__ rp,
        const int2* __restrict__ pcv, const float* __restrict__ t,
        float* __restrict__ h0, const float* __restrict__ eps, int l) {
    int w = blockIdx.x * 4 + (threadIdx.x >> 6);
    int lane = threadIdx.x & 63;
    if (w >= NN) return;
    int s = rp[w], e = rp[w + 1];
    float acc = 0.0f;
    for (int k = s; k < e; ++k) {
        int2 cv = pcv[k];                       // wave-uniform 8B broadcast
        float hv = t[(size_t)cv.x * HC + lane]; // coalesced 256B gather
        acc = fmaf(__int_as_float(cv.y), hv, acc);
    }
    float hnew = acc > 0.0f ? acc : expm1f(acc);
    int d = w % 3;
    float gate = 1.0f + tanhf(eps[l * 3 + d]);
    size_t idx = (size_t)w * HC + lane;
    h0[idx] = gate * h0[idx] - hnew;
}

// ---------------- lin2 + log_softmax
__global__ __launch_bounds__(256) void lin2_logsoftmax(const float* __restrict__ h,
        const float* __restrict__ W, const float* __restrict__ b,
        float* __restrict__ out) {
    int wid = blockIdx.x * 4 + (threadIdx.x >> 6);
    int lane = threadIdx.x & 63;
    if (wid >= G_N) return;
    float acc = 0.0f;
    const float* hr = h + (size_t)wid * 192;
    if (lane < OUT_DIM) {
        const float* wr_ = W + (size_t)lane * 192;
        #pragma unroll 4
        for (int k = 0; k < 192; k += 4) {
            float4 hv = *(const float4*)(hr + k);
            float4 wv = *(const float4*)(wr_ + k);
            acc = fmaf(hv.x, wv.x, acc);
            acc = fmaf(hv.y, wv.y, acc);
            acc = fmaf(hv.z, wv.z, acc);
            acc = fmaf(hv.w, wv.w, acc);
        }
        acc += b[lane];
    }
    float m = (lane < OUT_DIM) ? acc : -INFINITY;
    #pragma unroll
    for (int off = 32; off; off >>= 1) m = fmaxf(m, __shfl_xor(m, off));
    float e = (lane < OUT_DIM) ? expf(acc - m) : 0.0f;
    float s = e;
    #pragma unroll
    for (int off = 32; off; off >>= 1) s += __shfl_xor(s, off);
    if (lane < OUT_DIM) out[(size_t)wid * OUT_DIM + lane] = acc - m - logf(s);
}

extern "C" void kernel_launch(void* const* d_in, const int* in_sizes, int n_in,
                              void* d_out, int out_size, void* d_ws, size_t ws_size,
                              hipStream_t stream) {
    const float* x      = (const float*)d_in[0];
    const int*   rows   = (const int*)d_in[1];
    const int*   cols   = (const int*)d_in[2];
    const float* vals   = (const float*)d_in[3];
    const float* lin1_w = (const float*)d_in[4];
    const float* lin1_b = (const float*)d_in[5];
    const float* left_w = (const float*)d_in[6];
    const float* right_w= (const float*)d_in[7];
    const float* eps    = (const float*)d_in[8];
    const float* lin2_w = (const float*)d_in[9];
    const float* lin2_b = (const float*)d_in[10];
    float* out = (float*)d_out;

    size_t bufElems = (size_t)NN * HC;   // 9.6M floats
    float* h0   = (float*)d_ws;
    float* t    = h0 + bufElems;
    int*   rp   = (int*)(t + bufElems);  // NN+1
    int*   wo   = rp + 150016;           // NN
    int*   bsum = wo + 150016;           // 256
    int2*  pcv  = (int2*)(bsum + 256);   // NNZV int2 (8B-aligned: offset is even #ints)

    dim3 b256(256);
    const int NB_SCAN = (NN + 1023) / 1024;       // 147

    // --- CSR build (once; reused by all 4 layers) ---
    hipMemsetAsync(wo, 0, (size_t)NN * sizeof(int), stream);
    hist_k<<<dim3((NNZV + 255) / 256), b256, 0, stream>>>(rows, wo);
    scan_block_k<<<dim3(NB_SCAN), b256, 0, stream>>>(wo, rp, bsum);
    scan_top_k<<<dim3(1), b256, 0, stream>>>(bsum, NB_SCAN);
    scan_add_k<<<dim3((NN + 256) / 256 + 1), b256, 0, stream>>>(rp, bsum);
    hipMemcpyAsync(wo, rp, (size_t)NN * sizeof(int), hipMemcpyDeviceToDevice, stream);
    scatter_k<<<dim3((NNZV + 255) / 256), b256, 0, stream>>>(rows, cols, vals, wo, pcv);

    // --- lin1 -> h0 ---
    lin1_gemm<<<dim3((G_N + 63) / 64, 3), b256, 0, stream>>>(x, lin1_w, lin1_b, h0);

    for (int l = 0; l < NL; ++l) {
        transform_gemm<<<dim3((NN + 63) / 64), b256, 0, stream>>>(
            h0, left_w + l * 9, right_w + l * HC * HC, t);
        spmm_csr_fused<<<dim3((NN + 3) / 4), b256, 0, stream>>>(rp, pcv, t, h0, eps, l);
    }

    lin2_logsoftmax<<<dim3((G_N + 3) / 4), b256, 0, stream>>>(h0, lin2_w, lin2_b, out);
}

// Round 3
// 1014.738 us; speedup vs baseline: 2.6380x; 1.6890x over previous
//
#include <hip/hip_runtime.h>
#include <math.h>

#define G_N 50000
#define D_S 3
#define HC 64
#define IN_DIM 256
#define OUT_DIM 40
#define NL 4
#define NNZV 2400000
#define NN (G_N * D_S)   // 150000

__device__ __forceinline__ float elu_f(float v) {
    return v > 0.0f ? v : expm1f(v);
}

// ---------------- lin1: out[g, j] = elu(sum_k x[g,k] * W[j,k] + b[j])
__global__ __launch_bounds__(256) void lin1_gemm(const float* __restrict__ x,
        const float* __restrict__ W, const float* __restrict__ b,
        float* __restrict__ out) {
    const int K = IN_DIM;
    __shared__ float As[32][65];
    __shared__ float Bs[32][65];
    int tid = threadIdx.x;
    int tx = tid & 15, ty = tid >> 4;
    int m0 = blockIdx.x * 64;
    int n0 = blockIdx.y * 64;

    float acc[4][4] = {};
    int kslot = tid & 7;
    int row   = tid >> 3;

    for (int k0 = 0; k0 < K; k0 += 32) {
        #pragma unroll
        for (int pass = 0; pass < 2; ++pass) {
            int r = row + pass * 32;
            int gr = m0 + r;
            float4 v = make_float4(0.f, 0.f, 0.f, 0.f);
            if (gr < G_N) v = *(const float4*)(x + (size_t)gr * K + k0 + kslot * 4);
            As[kslot*4+0][r] = v.x; As[kslot*4+1][r] = v.y;
            As[kslot*4+2][r] = v.z; As[kslot*4+3][r] = v.w;

            int j = r;
            float4 w4 = *(const float4*)(W + (size_t)(n0 + j) * K + k0 + kslot * 4);
            Bs[kslot*4+0][j] = w4.x; Bs[kslot*4+1][j] = w4.y;
            Bs[kslot*4+2][j] = w4.z; Bs[kslot*4+3][j] = w4.w;
        }
        __syncthreads();
        #pragma unroll 8
        for (int k = 0; k < 32; ++k) {
            float4 a4 = *(const float4*)&As[k][ty*4];
            float4 b4 = *(const float4*)&Bs[k][tx*4];
            float av[4] = {a4.x, a4.y, a4.z, a4.w};
            float bv[4] = {b4.x, b4.y, b4.z, b4.w};
            #pragma unroll
            for (int i = 0; i < 4; ++i)
                #pragma unroll
                for (int j = 0; j < 4; ++j)
                    acc[i][j] = fmaf(av[i], bv[j], acc[i][j]);
        }
        __syncthreads();
    }

    float4 bias = *(const float4*)(b + n0 + tx*4);
    float bi[4] = {bias.x, bias.y, bias.z, bias.w};
    #pragma unroll
    for (int i = 0; i < 4; ++i) {
        int gr = m0 + ty*4 + i;
        if (gr < G_N) {
            float4 o;
            o.x = elu_f(acc[i][0] + bi[0]);
            o.y = elu_f(acc[i][1] + bi[1]);
            o.z = elu_f(acc[i][2] + bi[2]);
            o.w = elu_f(acc[i][3] + bi[3]);
            *(float4*)(out + (size_t)gr * 192 + n0 + tx*4) = o;
        }
    }
}

// ---------------- transform: out[n,j] = sum_c A[n,c]*Wr[j,c];  A[g*3+e,c] = sum_d lw[e,d]*h0[g*3+d,c]
__global__ __launch_bounds__(256) void transform_gemm(const float* __restrict__ h0,
        const float* __restrict__ lw, const float* __restrict__ Wr,
        float* __restrict__ out) {
    __shared__ float As[64][65];
    __shared__ float Bs[64][65];
    int tid = threadIdx.x;
    int tx = tid & 15, ty = tid >> 4;
    int r0 = blockIdx.x * 64;

    float L[9];
    #pragma unroll
    for (int i = 0; i < 9; ++i) L[i] = lw[i];

    int kslot = tid & 15;
    int rr    = tid >> 4;

    #pragma unroll
    for (int pass = 0; pass < 4; ++pass) {
        int r = rr + pass * 16;
        int gr = r0 + r;
        float4 v = make_float4(0.f, 0.f, 0.f, 0.f);
        if (gr < NN) {
            int g = gr / 3;
            int e = gr - g * 3;
            const float* base = h0 + (size_t)(g * 3) * HC + kslot * 4;
            float4 a0 = *(const float4*)(base);
            float4 a1 = *(const float4*)(base + HC);
            float4 a2 = *(const float4*)(base + 2 * HC);
            float l0 = L[e*3+0], l1 = L[e*3+1], l2 = L[e*3+2];
            v.x = l0*a0.x + l1*a1.x + l2*a2.x;
            v.y = l0*a0.y + l1*a1.y + l2*a2.y;
            v.z = l0*a0.z + l1*a1.z + l2*a2.z;
            v.w = l0*a0.w + l1*a1.w + l2*a2.w;
        }
        As[kslot*4+0][r] = v.x; As[kslot*4+1][r] = v.y;
        As[kslot*4+2][r] = v.z; As[kslot*4+3][r] = v.w;

        int j = r;
        float4 w4 = *(const float4*)(Wr + (size_t)j * HC + kslot * 4);
        Bs[kslot*4+0][j] = w4.x; Bs[kslot*4+1][j] = w4.y;
        Bs[kslot*4+2][j] = w4.z; Bs[kslot*4+3][j] = w4.w;
    }
    __syncthreads();

    float acc[4][4] = {};
    #pragma unroll 8
    for (int k = 0; k < 64; ++k) {
        float4 a4 = *(const float4*)&As[k][ty*4];
        float4 b4 = *(const float4*)&Bs[k][tx*4];
        float av[4] = {a4.x, a4.y, a4.z, a4.w};
        float bv[4] = {b4.x, b4.y, b4.z, b4.w};
        #pragma unroll
        for (int i = 0; i < 4; ++i)
            #pragma unroll
            for (int j = 0; j < 4; ++j)
                acc[i][j] = fmaf(av[i], bv[j], acc[i][j]);
    }

    #pragma unroll
    for (int i = 0; i < 4; ++i) {
        int gr = r0 + ty*4 + i;
        if (gr < NN) {
            float4 o = make_float4(acc[i][0], acc[i][1], acc[i][2], acc[i][3]);
            *(float4*)(out + (size_t)gr * HC + tx*4) = o;
        }
    }
}

// ---------------- CSR build ----------------
__global__ __launch_bounds__(256) void hist_k(const int* __restrict__ rows, int* __restrict__ cnt) {
    int i = blockIdx.x * 256 + threadIdx.x;
    if (i < NNZV) atomicAdd(&cnt[rows[i]], 1);
}

__global__ __launch_bounds__(256) void scan_block_k(const int* __restrict__ cnt,
        int* __restrict__ rp, int* __restrict__ bsum) {
    __shared__ int s[256];
    int base = blockIdx.x * 1024;
    int t = threadIdx.x;
    int v[4]; int sum = 0;
    #pragma unroll
    for (int j = 0; j < 4; ++j) {
        int idx = base + t * 4 + j;
        v[j] = (idx < NN) ? cnt[idx] : 0;
        sum += v[j];
    }
    s[t] = sum; __syncthreads();
    #pragma unroll
    for (int off = 1; off < 256; off <<= 1) {
        int x = 0;
        if (t >= off) x = s[t - off];
        __syncthreads();
        if (t >= off) s[t] += x;
        __syncthreads();
    }
    int excl = s[t] - sum;
    if (t == 255) bsum[blockIdx.x] = s[255];
    int run = excl;
    #pragma unroll
    for (int j = 0; j < 4; ++j) {
        int idx = base + t * 4 + j;
        if (idx < NN) rp[idx] = run;
        run += v[j];
    }
}

__global__ __launch_bounds__(256) void scan_top_k(int* __restrict__ bsum, int nb) {
    __shared__ int s[256];
    int t = threadIdx.x;
    int v = (t < nb) ? bsum[t] : 0;
    s[t] = v; __syncthreads();
    #pragma unroll
    for (int off = 1; off < 256; off <<= 1) {
        int x = 0;
        if (t >= off) x = s[t - off];
        __syncthreads();
        if (t >= off) s[t] += x;
        __syncthreads();
    }
    if (t < nb) bsum[t] = s[t] - v;
}

__global__ __launch_bounds__(256) void scan_add_k(int* __restrict__ rp, const int* __restrict__ bsum) {
    int idx = blockIdx.x * 256 + threadIdx.x;
    if (idx < NN) rp[idx] += bsum[idx >> 10];
    else if (idx == NN) rp[NN] = NNZV;
}

__global__ __launch_bounds__(256) void scatter_k(const int* __restrict__ rows,
        const int* __restrict__ cols, const float* __restrict__ vals,
        int* __restrict__ wo, int2* __restrict__ pcv) {
    int i = blockIdx.x * 256 + threadIdx.x;
    if (i < NNZV) {
        int r = rows[i];
        int p = atomicAdd(&wo[r], 1);
        pcv[p] = make_int2(cols[i], __float_as_int(vals[i]));
    }
}

// ---------------- fused CSR SpMM + elu + gated residual: h0 = gate*h0 - elu(L@t)
// one wave per row; lanes cooperatively load the row's (col,val) list, broadcast via shfl
__global__ __launch_bounds__(256) void spmm_csr_fused(const int* __restrict__ rp,
        const int2* __restrict__ pcv, const float* __restrict__ t,
        float* __restrict__ h0, const float* __restrict__ eps, int l) {
    int w = blockIdx.x * 4 + (threadIdx.x >> 6);
    int lane = threadIdx.x & 63;
    if (w >= NN) return;
    int s = rp[w], e = rp[w + 1];
    float acc0 = 0.0f, acc1 = 0.0f;
    for (int cb = s; cb < e; cb += 64) {
        int n = e - cb; if (n > 64) n = 64;
        int2 cv = make_int2(0, 0);
        if (lane < n) cv = pcv[cb + lane];      // coalesced: whole row in one load
        int j = 0;
        for (; j + 1 < n; j += 2) {
            int   c0 = __shfl(cv.x, j);
            float v0 = __int_as_float(__shfl(cv.y, j));
            int   c1 = __shfl(cv.x, j + 1);
            float v1 = __int_as_float(__shfl(cv.y, j + 1));
            float h0v = t[(size_t)c0 * HC + lane];   // independent in-flight gathers
            float h1v = t[(size_t)c1 * HC + lane];
            acc0 = fmaf(v0, h0v, acc0);
            acc1 = fmaf(v1, h1v, acc1);
        }
        if (j < n) {
            int   c0 = __shfl(cv.x, j);
            float v0 = __int_as_float(__shfl(cv.y, j));
            acc0 = fmaf(v0, t[(size_t)c0 * HC + lane], acc0);
        }
    }
    float acc = acc0 + acc1;
    float hnew = acc > 0.0f ? acc : expm1f(acc);
    int d = w % 3;
    float gate = 1.0f + tanhf(eps[l * 3 + d]);
    size_t idx = (size_t)w * HC + lane;
    h0[idx] = gate * h0[idx] - hnew;
}

// ---------------- lin2 (tiled GEMM, N padded 40->64) + fused log_softmax
__global__ __launch_bounds__(256) void lin2_ls_gemm(const float* __restrict__ h,
        const float* __restrict__ W, const float* __restrict__ b,
        float* __restrict__ out) {
    const int K = 192;
    __shared__ float As[32][65];
    __shared__ float Bs[32][65];
    int tid = threadIdx.x;
    int tx = tid & 15, ty = tid >> 4;
    int m0 = blockIdx.x * 64;

    float acc[4][4] = {};
    int kslot = tid & 7;
    int row   = tid >> 3;

    for (int k0 = 0; k0 < K; k0 += 32) {
        #pragma unroll
        for (int pass = 0; pass < 2; ++pass) {
            int r = row + pass * 32;
            int gr = m0 + r;
            float4 v = make_float4(0.f, 0.f, 0.f, 0.f);
            if (gr < G_N) v = *(const float4*)(h + (size_t)gr * K + k0 + kslot * 4);
            As[kslot*4+0][r] = v.x; As[kslot*4+1][r] = v.y;
            As[kslot*4+2][r] = v.z; As[kslot*4+3][r] = v.w;

            int j = r;
            float4 w4 = make_float4(0.f, 0.f, 0.f, 0.f);
            if (j < OUT_DIM) w4 = *(const float4*)(W + (size_t)j * K + k0 + kslot * 4);
            Bs[kslot*4+0][j] = w4.x; Bs[kslot*4+1][j] = w4.y;
            Bs[kslot*4+2][j] = w4.z; Bs[kslot*4+3][j] = w4.w;
        }
        __syncthreads();
        #pragma unroll 8
        for (int k = 0; k < 32; ++k) {
            float4 a4 = *(const float4*)&As[k][ty*4];
            float4 b4 = *(const float4*)&Bs[k][tx*4];
            float av[4] = {a4.x, a4.y, a4.z, a4.w};
            float bv[4] = {b4.x, b4.y, b4.z, b4.w};
            #pragma unroll
            for (int i = 0; i < 4; ++i)
                #pragma unroll
                for (int j = 0; j < 4; ++j)
                    acc[i][j] = fmaf(av[i], bv[j], acc[i][j]);
        }
        __syncthreads();
    }

    bool validc = (tx < 10);   // cols tx*4..tx*4+3 all < 40 iff tx < 10
    float bi[4];
    #pragma unroll
    for (int j = 0; j < 4; ++j) bi[j] = validc ? b[tx*4+j] : 0.0f;

    #pragma unroll
    for (int i = 0; i < 4; ++i) {
        int gr = m0 + ty*4 + i;
        float v[4];
        float mymax = -INFINITY;
        #pragma unroll
        for (int j = 0; j < 4; ++j) {
            v[j] = acc[i][j] + bi[j];
            if (validc) mymax = fmaxf(mymax, v[j]);
        }
        #pragma unroll
        for (int off = 1; off < 16; off <<= 1) mymax = fmaxf(mymax, __shfl_xor(mymax, off));
        float s = 0.0f;
        if (validc) {
            #pragma unroll
            for (int j = 0; j < 4; ++j) s += expf(v[j] - mymax);
        }
        #pragma unroll
        for (int off = 1; off < 16; off <<= 1) s += __shfl_xor(s, off);
        float lse = mymax + logf(s);
        if (gr < G_N && validc) {
            float4 o = make_float4(v[0]-lse, v[1]-lse, v[2]-lse, v[3]-lse);
            *(float4*)(out + (size_t)gr * OUT_DIM + tx*4) = o;
        }
    }
}

extern "C" void kernel_launch(void* const* d_in, const int* in_sizes, int n_in,
                              void* d_out, int out_size, void* d_ws, size_t ws_size,
                              hipStream_t stream) {
    const float* x      = (const float*)d_in[0];
    const int*   rows   = (const int*)d_in[1];
    const int*   cols   = (const int*)d_in[2];
    const float* vals   = (const float*)d_in[3];
    const float* lin1_w = (const float*)d_in[4];
    const float* lin1_b = (const float*)d_in[5];
    const float* left_w = (const float*)d_in[6];
    const float* right_w= (const float*)d_in[7];
    const float* eps    = (const float*)d_in[8];
    const float* lin2_w = (const float*)d_in[9];
    const float* lin2_b = (const float*)d_in[10];
    float* out = (float*)d_out;

    size_t bufElems = (size_t)NN * HC;   // 9.6M floats
    float* h0   = (float*)d_ws;
    float* t    = h0 + bufElems;
    int*   rp   = (int*)(t + bufElems);  // NN+1
    int*   wo   = rp + 150016;           // NN
    int*   bsum = wo + 150016;           // 256
    int2*  pcv  = (int2*)(bsum + 256);   // NNZV int2

    dim3 b256(256);
    const int NB_SCAN = (NN + 1023) / 1024;       // 147

    // --- CSR build (once; reused by all 4 layers) ---
    hipMemsetAsync(wo, 0, (size_t)NN * sizeof(int), stream);
    hist_k<<<dim3((NNZV + 255) / 256), b256, 0, stream>>>(rows, wo);
    scan_block_k<<<dim3(NB_SCAN), b256, 0, stream>>>(wo, rp, bsum);
    scan_top_k<<<dim3(1), b256, 0, stream>>>(bsum, NB_SCAN);
    scan_add_k<<<dim3((NN + 256) / 256 + 1), b256, 0, stream>>>(rp, bsum);
    hipMemcpyAsync(wo, rp, (size_t)NN * sizeof(int), hipMemcpyDeviceToDevice, stream);
    scatter_k<<<dim3((NNZV + 255) / 256), b256, 0, stream>>>(rows, cols, vals, wo, pcv);

    // --- lin1 -> h0 ---
    lin1_gemm<<<dim3((G_N + 63) / 64, 3), b256, 0, stream>>>(x, lin1_w, lin1_b, h0);

    for (int l = 0; l < NL; ++l) {
        transform_gemm<<<dim3((NN + 63) / 64), b256, 0, stream>>>(
            h0, left_w + l * 9, right_w + l * HC * HC, t);
        spmm_csr_fused<<<dim3((NN + 3) / 4), b256, 0, stream>>>(rp, pcv, t, h0, eps, l);
    }

    lin2_ls_gemm<<<dim3((G_N + 63) / 64), b256, 0, stream>>>(h0, lin2_w, lin2_b, out);
}

// Round 4
// 765.275 us; speedup vs baseline: 3.4980x; 1.3260x over previous
//
#include <hip/hip_runtime.h>
#include <math.h>

#define G_N 50000
#define D_S 3
#define HC 64
#define IN_DIM 256
#define OUT_DIM 40
#define NL 4
#define NNZV 2400000
#define NN (G_N * D_S)   // 150000
#define NGRP 8
#define ROWS_PER_GRP (NN / NGRP)   // 18750

__device__ __forceinline__ float elu_f(float v) {
    return v > 0.0f ? v : expm1f(v);
}

__device__ __forceinline__ unsigned short f2bf(float f) {
    unsigned u = __float_as_uint(f);
    return (unsigned short)((u + 0x7FFF + ((u >> 16) & 1)) >> 16);
}

// ---------------- lin1: out[g, j] = elu(sum_k x[g,k] * W[j,k] + b[j])
__global__ __launch_bounds__(256) void lin1_gemm(const float* __restrict__ x,
        const float* __restrict__ W, const float* __restrict__ b,
        float* __restrict__ out) {
    const int K = IN_DIM;
    __shared__ float As[32][65];
    __shared__ float Bs[32][65];
    int tid = threadIdx.x;
    int tx = tid & 15, ty = tid >> 4;
    int m0 = blockIdx.x * 64;
    int n0 = blockIdx.y * 64;

    float acc[4][4] = {};
    int kslot = tid & 7;
    int row   = tid >> 3;

    for (int k0 = 0; k0 < K; k0 += 32) {
        #pragma unroll
        for (int pass = 0; pass < 2; ++pass) {
            int r = row + pass * 32;
            int gr = m0 + r;
            float4 v = make_float4(0.f, 0.f, 0.f, 0.f);
            if (gr < G_N) v = *(const float4*)(x + (size_t)gr * K + k0 + kslot * 4);
            As[kslot*4+0][r] = v.x; As[kslot*4+1][r] = v.y;
            As[kslot*4+2][r] = v.z; As[kslot*4+3][r] = v.w;

            int j = r;
            float4 w4 = *(const float4*)(W + (size_t)(n0 + j) * K + k0 + kslot * 4);
            Bs[kslot*4+0][j] = w4.x; Bs[kslot*4+1][j] = w4.y;
            Bs[kslot*4+2][j] = w4.z; Bs[kslot*4+3][j] = w4.w;
        }
        __syncthreads();
        #pragma unroll 8
        for (int k = 0; k < 32; ++k) {
            float4 a4 = *(const float4*)&As[k][ty*4];
            float4 b4 = *(const float4*)&Bs[k][tx*4];
            float av[4] = {a4.x, a4.y, a4.z, a4.w};
            float bv[4] = {b4.x, b4.y, b4.z, b4.w};
            #pragma unroll
            for (int i = 0; i < 4; ++i)
                #pragma unroll
                for (int j = 0; j < 4; ++j)
                    acc[i][j] = fmaf(av[i], bv[j], acc[i][j]);
        }
        __syncthreads();
    }

    float4 bias = *(const float4*)(b + n0 + tx*4);
    float bi[4] = {bias.x, bias.y, bias.z, bias.w};
    #pragma unroll
    for (int i = 0; i < 4; ++i) {
        int gr = m0 + ty*4 + i;
        if (gr < G_N) {
            float4 o;
            o.x = elu_f(acc[i][0] + bi[0]);
            o.y = elu_f(acc[i][1] + bi[1]);
            o.z = elu_f(acc[i][2] + bi[2]);
            o.w = elu_f(acc[i][3] + bi[3]);
            *(float4*)(out + (size_t)gr * 192 + n0 + tx*4) = o;
        }
    }
}

// ---------------- transform: tb[n,j] = bf16( sum_c A[n,c]*Wr[j,c] );  A[g*3+e,c] = sum_d lw[e,d]*h0[g*3+d,c]
__global__ __launch_bounds__(256) void transform_gemm(const float* __restrict__ h0,
        const float* __restrict__ lw, const float* __restrict__ Wr,
        unsigned short* __restrict__ tb) {
    __shared__ float As[64][65];
    __shared__ float Bs[64][65];
    int tid = threadIdx.x;
    int tx = tid & 15, ty = tid >> 4;
    int r0 = blockIdx.x * 64;

    float L[9];
    #pragma unroll
    for (int i = 0; i < 9; ++i) L[i] = lw[i];

    int kslot = tid & 15;
    int rr    = tid >> 4;

    #pragma unroll
    for (int pass = 0; pass < 4; ++pass) {
        int r = rr + pass * 16;
        int gr = r0 + r;
        float4 v = make_float4(0.f, 0.f, 0.f, 0.f);
        if (gr < NN) {
            int g = gr / 3;
            int e = gr - g * 3;
            const float* base = h0 + (size_t)(g * 3) * HC + kslot * 4;
            float4 a0 = *(const float4*)(base);
            float4 a1 = *(const float4*)(base + HC);
            float4 a2 = *(const float4*)(base + 2 * HC);
            float l0 = L[e*3+0], l1 = L[e*3+1], l2 = L[e*3+2];
            v.x = l0*a0.x + l1*a1.x + l2*a2.x;
            v.y = l0*a0.y + l1*a1.y + l2*a2.y;
            v.z = l0*a0.z + l1*a1.z + l2*a2.z;
            v.w = l0*a0.w + l1*a1.w + l2*a2.w;
        }
        As[kslot*4+0][r] = v.x; As[kslot*4+1][r] = v.y;
        As[kslot*4+2][r] = v.z; As[kslot*4+3][r] = v.w;

        int j = r;
        float4 w4 = *(const float4*)(Wr + (size_t)j * HC + kslot * 4);
        Bs[kslot*4+0][j] = w4.x; Bs[kslot*4+1][j] = w4.y;
        Bs[kslot*4+2][j] = w4.z; Bs[kslot*4+3][j] = w4.w;
    }
    __syncthreads();

    float acc[4][4] = {};
    #pragma unroll 8
    for (int k = 0; k < 64; ++k) {
        float4 a4 = *(const float4*)&As[k][ty*4];
        float4 b4 = *(const float4*)&Bs[k][tx*4];
        float av[4] = {a4.x, a4.y, a4.z, a4.w};
        float bv[4] = {b4.x, b4.y, b4.z, b4.w};
        #pragma unroll
        for (int i = 0; i < 4; ++i)
            #pragma unroll
            for (int j = 0; j < 4; ++j)
                acc[i][j] = fmaf(av[i], bv[j], acc[i][j]);
    }

    #pragma unroll
    for (int i = 0; i < 4; ++i) {
        int gr = r0 + ty*4 + i;
        if (gr < NN) {
            ushort4 o;
            o.x = f2bf(acc[i][0]); o.y = f2bf(acc[i][1]);
            o.z = f2bf(acc[i][2]); o.w = f2bf(acc[i][3]);
            *(ushort4*)(tb + (size_t)gr * HC + tx*4) = o;
        }
    }
}

// ---------------- CSR build (XCD row-range localized) ----------------
__global__ __launch_bounds__(256) void hist_grp_k(const int* __restrict__ rows,
        int* __restrict__ cnt) {
    int g = blockIdx.x & 7;            // group == expected XCD (round-robin dispatch)
    int s = blockIdx.x >> 3;
    int lo = g * ROWS_PER_GRP, hi = lo + ROWS_PER_GRP;
    int stride = (gridDim.x >> 3) * 256;
    for (int i = s * 256 + threadIdx.x; i < NNZV; i += stride) {
        int r = rows[i];
        if (r >= lo && r < hi) atomicAdd(&cnt[r], 1);
    }
}

__global__ __launch_bounds__(256) void scan_block_k(const int* __restrict__ cnt,
        int* __restrict__ rp, int* __restrict__ bsum) {
    __shared__ int s[256];
    int base = blockIdx.x * 1024;
    int t = threadIdx.x;
    int v[4]; int sum = 0;
    #pragma unroll
    for (int j = 0; j < 4; ++j) {
        int idx = base + t * 4 + j;
        v[j] = (idx < NN) ? cnt[idx] : 0;
        sum += v[j];
    }
    s[t] = sum; __syncthreads();
    #pragma unroll
    for (int off = 1; off < 256; off <<= 1) {
        int x = 0;
        if (t >= off) x = s[t - off];
        __syncthreads();
        if (t >= off) s[t] += x;
        __syncthreads();
    }
    int excl = s[t] - sum;
    if (t == 255) bsum[blockIdx.x] = s[255];
    int run = excl;
    #pragma unroll
    for (int j = 0; j < 4; ++j) {
        int idx = base + t * 4 + j;
        if (idx < NN) rp[idx] = run;
        run += v[j];
    }
}

__global__ __launch_bounds__(256) void scan_top_k(int* __restrict__ bsum, int nb) {
    __shared__ int s[256];
    int t = threadIdx.x;
    int v = (t < nb) ? bsum[t] : 0;
    s[t] = v; __syncthreads();
    #pragma unroll
    for (int off = 1; off < 256; off <<= 1) {
        int x = 0;
        if (t >= off) x = s[t - off];
        __syncthreads();
        if (t >= off) s[t] += x;
        __syncthreads();
    }
    if (t < nb) bsum[t] = s[t] - v;
}

__global__ __launch_bounds__(256) void scan_add_k(int* __restrict__ rp, const int* __restrict__ bsum) {
    int idx = blockIdx.x * 256 + threadIdx.x;
    if (idx < NN) rp[idx] += bsum[idx >> 10];
    else if (idx == NN) rp[NN] = NNZV;
}

__global__ __launch_bounds__(256) void scatter_grp_k(const int* __restrict__ rows,
        const int* __restrict__ cols, const float* __restrict__ vals,
        int* __restrict__ wo, int2* __restrict__ pcv) {
    int g = blockIdx.x & 7;
    int s = blockIdx.x >> 3;
    int lo = g * ROWS_PER_GRP, hi = lo + ROWS_PER_GRP;
    int stride = (gridDim.x >> 3) * 256;
    for (int i = s * 256 + threadIdx.x; i < NNZV; i += stride) {
        int r = rows[i];
        if (r >= lo && r < hi) {
            int p = atomicAdd(&wo[r], 1);
            pcv[p] = make_int2(cols[i], __float_as_int(vals[i]));
        }
    }
}

// ---------------- fused CSR SpMM + elu + gated residual: h0 = gate*h0 - elu(L@t)
// one wave per row; lanes cooperatively load (col,val), broadcast via shfl; 8 gathers in flight
__global__ __launch_bounds__(256) void spmm_csr_fused(const int* __restrict__ rp,
        const int2* __restrict__ pcv, const unsigned short* __restrict__ tb,
        float* __restrict__ h0, const float* __restrict__ eps, int l) {
    int w = blockIdx.x * 4 + (threadIdx.x >> 6);
    int lane = threadIdx.x & 63;
    if (w >= NN) return;
    int s = rp[w], e = rp[w + 1];
    float acc = 0.0f;
    for (int cb = s; cb < e; cb += 64) {
        int n = e - cb; if (n > 64) n = 64;
        int2 cv = make_int2(0, 0);                 // lanes >= n: col 0 / val 0 -> harmless
        if (lane < n) cv = pcv[cb + lane];
        for (int j0 = 0; j0 < n; j0 += 8) {
            float hv[8], vv[8];
            #pragma unroll
            for (int u = 0; u < 8; ++u) {
                int   c = __shfl(cv.x, j0 + u);
                vv[u]   = __int_as_float(__shfl(cv.y, j0 + u));
                hv[u]   = __uint_as_float((unsigned)tb[(size_t)c * HC + lane] << 16);
            }
            #pragma unroll
            for (int u = 0; u < 8; ++u) acc = fmaf(vv[u], hv[u], acc);
        }
    }
    float hnew = acc > 0.0f ? acc : expm1f(acc);
    int d = w % 3;
    float gate = 1.0f + tanhf(eps[l * 3 + d]);
    size_t idx = (size_t)w * HC + lane;
    h0[idx] = gate * h0[idx] - hnew;
}

// ---------------- lin2 (tiled GEMM, N padded 40->64) + fused log_softmax
__global__ __launch_bounds__(256) void lin2_ls_gemm(const float* __restrict__ h,
        const float* __restrict__ W, const float* __restrict__ b,
        float* __restrict__ out) {
    const int K = 192;
    __shared__ float As[32][65];
    __shared__ float Bs[32][65];
    int tid = threadIdx.x;
    int tx = tid & 15, ty = tid >> 4;
    int m0 = blockIdx.x * 64;

    float acc[4][4] = {};
    int kslot = tid & 7;
    int row   = tid >> 3;

    for (int k0 = 0; k0 < K; k0 += 32) {
        #pragma unroll
        for (int pass = 0; pass < 2; ++pass) {
            int r = row + pass * 32;
            int gr = m0 + r;
            float4 v = make_float4(0.f, 0.f, 0.f, 0.f);
            if (gr < G_N) v = *(const float4*)(h + (size_t)gr * K + k0 + kslot * 4);
            As[kslot*4+0][r] = v.x; As[kslot*4+1][r] = v.y;
            As[kslot*4+2][r] = v.z; As[kslot*4+3][r] = v.w;

            int j = r;
            float4 w4 = make_float4(0.f, 0.f, 0.f, 0.f);
            if (j < OUT_DIM) w4 = *(const float4*)(W + (size_t)j * K + k0 + kslot * 4);
            Bs[kslot*4+0][j] = w4.x; Bs[kslot*4+1][j] = w4.y;
            Bs[kslot*4+2][j] = w4.z; Bs[kslot*4+3][j] = w4.w;
        }
        __syncthreads();
        #pragma unroll 8
        for (int k = 0; k < 32; ++k) {
            float4 a4 = *(const float4*)&As[k][ty*4];
            float4 b4 = *(const float4*)&Bs[k][tx*4];
            float av[4] = {a4.x, a4.y, a4.z, a4.w};
            float bv[4] = {b4.x, b4.y, b4.z, b4.w};
            #pragma unroll
            for (int i = 0; i < 4; ++i)
                #pragma unroll
                for (int j = 0; j < 4; ++j)
                    acc[i][j] = fmaf(av[i], bv[j], acc[i][j]);
        }
        __syncthreads();
    }

    bool validc = (tx < 10);
    float bi[4];
    #pragma unroll
    for (int j = 0; j < 4; ++j) bi[j] = validc ? b[tx*4+j] : 0.0f;

    #pragma unroll
    for (int i = 0; i < 4; ++i) {
        int gr = m0 + ty*4 + i;
        float v[4];
        float mymax = -INFINITY;
        #pragma unroll
        for (int j = 0; j < 4; ++j) {
            v[j] = acc[i][j] + bi[j];
            if (validc) mymax = fmaxf(mymax, v[j]);
        }
        #pragma unroll
        for (int off = 1; off < 16; off <<= 1) mymax = fmaxf(mymax, __shfl_xor(mymax, off));
        float s = 0.0f;
        if (validc) {
            #pragma unroll
            for (int j = 0; j < 4; ++j) s += expf(v[j] - mymax);
        }
        #pragma unroll
        for (int off = 1; off < 16; off <<= 1) s += __shfl_xor(s, off);
        float lse = mymax + logf(s);
        if (gr < G_N && validc) {
            float4 o = make_float4(v[0]-lse, v[1]-lse, v[2]-lse, v[3]-lse);
            *(float4*)(out + (size_t)gr * OUT_DIM + tx*4) = o;
        }
    }
}

extern "C" void kernel_launch(void* const* d_in, const int* in_sizes, int n_in,
                              void* d_out, int out_size, void* d_ws, size_t ws_size,
                              hipStream_t stream) {
    const float* x      = (const float*)d_in[0];
    const int*   rows   = (const int*)d_in[1];
    const int*   cols   = (const int*)d_in[2];
    const float* vals   = (const float*)d_in[3];
    const float* lin1_w = (const float*)d_in[4];
    const float* lin1_b = (const float*)d_in[5];
    const float* left_w = (const float*)d_in[6];
    const float* right_w= (const float*)d_in[7];
    const float* eps    = (const float*)d_in[8];
    const float* lin2_w = (const float*)d_in[9];
    const float* lin2_b = (const float*)d_in[10];
    float* out = (float*)d_out;

    size_t bufElems = (size_t)NN * HC;                 // 9.6M
    float* h0 = (float*)d_ws;                          // 38.4 MB
    unsigned short* tb = (unsigned short*)(h0 + bufElems); // 19.2 MB (bf16)
    int*   rp   = (int*)(tb + bufElems);               // NN+1
    int*   wo   = rp + 150016;
    int*   bsum = wo + 150016;
    int2*  pcv  = (int2*)(bsum + 256);                 // 19.2 MB

    dim3 b256(256);
    const int NB_SCAN = (NN + 1023) / 1024;            // 147
    const int NB_GRP  = 8 * 2344;                      // 8 groups x full-input scan

    // --- CSR build (once; reused by all 4 layers) ---
    hipMemsetAsync(wo, 0, (size_t)NN * sizeof(int), stream);
    hist_grp_k<<<dim3(NB_GRP), b256, 0, stream>>>(rows, wo);
    scan_block_k<<<dim3(NB_SCAN), b256, 0, stream>>>(wo, rp, bsum);
    scan_top_k<<<dim3(1), b256, 0, stream>>>(bsum, NB_SCAN);
    scan_add_k<<<dim3((NN + 256) / 256 + 1), b256, 0, stream>>>(rp, bsum);
    hipMemcpyAsync(wo, rp, (size_t)NN * sizeof(int), hipMemcpyDeviceToDevice, stream);
    scatter_grp_k<<<dim3(NB_GRP), b256, 0, stream>>>(rows, cols, vals, wo, pcv);

    // --- lin1 -> h0 ---
    lin1_gemm<<<dim3((G_N + 63) / 64, 3), b256, 0, stream>>>(x, lin1_w, lin1_b, h0);

    for (int l = 0; l < NL; ++l) {
        transform_gemm<<<dim3((NN + 63) / 64), b256, 0, stream>>>(
            h0, left_w + l * 9, right_w + l * HC * HC, tb);
        spmm_csr_fused<<<dim3((NN + 3) / 4), b256, 0, stream>>>(rp, pcv, tb, h0, eps, l);
    }

    lin2_ls_gemm<<<dim3((G_N + 63) / 64), b256, 0, stream>>>(h0, lin2_w, lin2_b, out);
}